// Round 9
// baseline (44.025 us; speedup 1.0000x reference)
//
#include <hip/hip_runtime.h>

#define NN 4
#define CC 128
#define HH 64
#define WW 64
#define KK 5
#define K2 25
#define HUP 128
#define WUP 128
#define CH2  (2 * HH * WW * 4)     // byte stride of 2 channels (cg2-interleave)
#define OCH2 (2 * HUP * WUP * 4)   // output byte stride of 2 channels

typedef int   v4i __attribute__((ext_vector_type(4)));
typedef float v4f __attribute__((ext_vector_type(4)));
typedef float v2f __attribute__((ext_vector_type(2)));

// Raw buffer ops: HW bounds-check (OOB load -> 0.0f, OOB store dropped).
__device__ float llvm_amdgcn_raw_buffer_load_fp32(v4i srsrc, int voffset,
                                                  int soffset, int aux)
    __asm("llvm.amdgcn.raw.buffer.load.f32");
__device__ v4f llvm_amdgcn_raw_buffer_load_v4f32(v4i srsrc, int voffset,
                                                 int soffset, int aux)
    __asm("llvm.amdgcn.raw.buffer.load.v4f32");
__device__ void llvm_amdgcn_raw_buffer_store_v2f32(v2f data, v4i srsrc,
                                                   int voffset, int soffset,
                                                   int aux)
    __asm("llvm.amdgcn.raw.buffer.store.v2f32");

__device__ inline v4i make_srd(const void* p, unsigned bytes) {
  union { const void* p; unsigned u[2]; } a;
  a.p = p;
  v4i r;
  r.x = (int)a.u[0];
  r.y = (int)(a.u[1] & 0xffffu);  // base[47:32], stride=0
  r.z = (int)bytes;               // num_records in bytes
  r.w = 0x00020000;               // raw dword access
  return r;
}

// grid: NN*HH*4 = 1024 blocks, 256 threads.
// block: cq = bid&3, h = (bid>>2)&63, n = bid>>8
// thread: w = t&63 (output cols 2w,2w+1), a = (t>>6)&1 (output row 2h+a),
//         cg2 = t>>7; channels c = cq*32 + ci*2 + cg2, ci = 0..15.
// Each thread owns a 1x2 output tile -> mreg = 25 v2f = 50 VGPRs (half of
// the 2x2 layout), targeting 5-6 waves/SIMD for latency hiding.
__global__ __launch_bounds__(256) void carafe_kernel(
    const float* __restrict__ feat, const float* __restrict__ masks,
    float* __restrict__ out) {
  const int bid = blockIdx.x;
  const int cq = bid & 3;
  const int h  = (bid >> 2) & (HH - 1);
  const int n  = bid >> 8;
  const int t  = threadIdx.x;
  const int w  = t & (WW - 1);
  const int a  = (t >> 6) & 1;
  const int cg2 = t >> 7;

  // Validity of window taps (zero-padding folded into the mask registers).
  float vi[KK], vj[KK];
#pragma unroll
  for (int i = 0; i < KK; ++i) {
    const int r = h - 2 + i;
    vi[i] = (r >= 0 && r < HH) ? 1.f : 0.f;
    const int x = w - 2 + i;
    vj[i] = (x >= 0 && x < WW) ? 1.f : 0.f;
  }

  // mreg[k] = {masks[n,k,2h+a,2w], masks[n,k,2h+a,2w+1]} * valid(i,j)
  v2f mreg[K2];
#pragma unroll
  for (int k = 0; k < K2; ++k) {
    const int i = k / KK, j = k % KK;
    const float vv = vi[i] * vj[j];
    const float2 mv = *reinterpret_cast<const float2*>(
        &masks[(((size_t)n * K2 + k) * HUP + (2 * h + a)) * WUP + 2 * w]);
    v2f m; m.x = mv.x * vv; m.y = mv.y * vv;
    mreg[k] = m;
  }

  const v4i srdF = make_srd(feat, (unsigned)(NN * CC * HH * WW) * 4u);
  const v4i srdO = make_srd(out,  (unsigned)(NN * CC * HUP * WUP) * 4u);

  const int c0 = cq * 32 + cg2;
  // Byte offset of window origin (h-2, w-2); negative only when c0==0 (ci=0).
  int vfb = (((n * CC + c0) * HH * WW) + (h - 2) * WW + (w - 2)) * 4;
  int vob = (((n * CC + c0) * HUP + 2 * h + a) * WUP + 2 * w) * 4;

#define FMA1(k, e)                                                       \
  do {                                                                   \
    v2f ff; ff.x = (e); ff.y = (e);                                      \
    acc += ff * mreg[k];                                                 \
  } while (0)

#define FMA5(kb, e0, e1, e2, e3, e4)                                     \
  do {                                                                   \
    FMA1((kb) + 0, (e0)); FMA1((kb) + 1, (e1)); FMA1((kb) + 2, (e2));    \
    FMA1((kb) + 3, (e3)); FMA1((kb) + 4, (e4));                          \
  } while (0)

  // --- ci = 0: scalar taps (negative voffset -> OOB -> 0 = zero padding),
  // row-split to cap live window regs. R4-proven addressing. ---
  {
    v2f acc = {0.f, 0.f};
    float fA[15];
#pragma unroll
    for (int i = 0; i < 3; ++i)
#pragma unroll
      for (int j = 0; j < KK; ++j)
        fA[i * KK + j] = llvm_amdgcn_raw_buffer_load_fp32(
            srdF, vfb + (i * WW + j) * 4, 0, 0);
    FMA5(0,  fA[0],  fA[1],  fA[2],  fA[3],  fA[4]);
    FMA5(5,  fA[5],  fA[6],  fA[7],  fA[8],  fA[9]);
    FMA5(10, fA[10], fA[11], fA[12], fA[13], fA[14]);

    float fB[10];
#pragma unroll
    for (int i = 0; i < 2; ++i)
#pragma unroll
      for (int j = 0; j < KK; ++j)
        fB[i * KK + j] = llvm_amdgcn_raw_buffer_load_fp32(
            srdF, vfb + ((i + 3) * WW + j) * 4, 0, 0);
    FMA5(15, fB[0], fB[1], fB[2], fB[3], fB[4]);
    FMA5(20, fB[5], fB[6], fB[7], fB[8], fB[9]);

    llvm_amdgcn_raw_buffer_store_v2f32(acc, srdO, vob, 0, 0);
  }

  // --- ci = 1..15: c >= 2 so voffsets positive; edge crossings read
  // in-bounds garbage annihilated by validity-zeroed masks. R4-proven
  // dwordx4 + scalar row loads. ---
#pragma unroll 1
  for (int ci = 1; ci < 16; ++ci) {
    vfb += CH2;
    vob += OCH2;

    v2f acc = {0.f, 0.f};

    const v4f r0 = llvm_amdgcn_raw_buffer_load_v4f32(srdF, vfb + 0 * WW * 4, 0, 0);
    const float s0 = llvm_amdgcn_raw_buffer_load_fp32(srdF, vfb + 0 * WW * 4 + 16, 0, 0);
    const v4f r1 = llvm_amdgcn_raw_buffer_load_v4f32(srdF, vfb + 1 * WW * 4, 0, 0);
    const float s1 = llvm_amdgcn_raw_buffer_load_fp32(srdF, vfb + 1 * WW * 4 + 16, 0, 0);
    const v4f r2 = llvm_amdgcn_raw_buffer_load_v4f32(srdF, vfb + 2 * WW * 4, 0, 0);
    const float s2 = llvm_amdgcn_raw_buffer_load_fp32(srdF, vfb + 2 * WW * 4 + 16, 0, 0);
    FMA5(0,  r0.x, r0.y, r0.z, r0.w, s0);
    FMA5(5,  r1.x, r1.y, r1.z, r1.w, s1);
    FMA5(10, r2.x, r2.y, r2.z, r2.w, s2);

    const v4f r3 = llvm_amdgcn_raw_buffer_load_v4f32(srdF, vfb + 3 * WW * 4, 0, 0);
    const float s3 = llvm_amdgcn_raw_buffer_load_fp32(srdF, vfb + 3 * WW * 4 + 16, 0, 0);
    const v4f r4 = llvm_amdgcn_raw_buffer_load_v4f32(srdF, vfb + 4 * WW * 4, 0, 0);
    const float s4 = llvm_amdgcn_raw_buffer_load_fp32(srdF, vfb + 4 * WW * 4 + 16, 0, 0);
    FMA5(15, r3.x, r3.y, r3.z, r3.w, s3);
    FMA5(20, r4.x, r4.y, r4.z, r4.w, s4);

    llvm_amdgcn_raw_buffer_store_v2f32(acc, srdO, vob, 0, 0);
  }
#undef FMA5
#undef FMA1
}

extern "C" void kernel_launch(void* const* d_in, const int* in_sizes, int n_in,
                              void* d_out, int out_size, void* d_ws, size_t ws_size,
                              hipStream_t stream) {
  const float* feat  = (const float*)d_in[0];
  const float* masks = (const float*)d_in[1];
  float* out = (float*)d_out;
  (void)in_sizes; (void)n_in; (void)out_size; (void)d_ws; (void)ws_size;
  carafe_kernel<<<NN * HH * 4, 256, 0, stream>>>(feat, masks, out);
}

// Round 10
// 21.456 us; speedup vs baseline: 2.0519x; 2.0519x over previous
//
#include <hip/hip_runtime.h>

#define NN 4
#define CC 128
#define HH 64
#define WW 64
#define KK 5
#define K2 25
#define HUP 128
#define WUP 128

typedef int   v4i __attribute__((ext_vector_type(4)));
typedef float v2f __attribute__((ext_vector_type(2)));

__device__ void llvm_amdgcn_raw_buffer_store_v2f32(v2f data, v4i srsrc,
                                                   int voffset, int soffset,
                                                   int aux)
    __asm("llvm.amdgcn.raw.buffer.store.v2f32");

__device__ inline v4i make_srd(const void* p, unsigned bytes) {
  union { const void* p; unsigned u[2]; } a;
  a.p = p;
  v4i r;
  r.x = (int)a.u[0];
  r.y = (int)(a.u[1] & 0xffffu);  // base[47:32], stride=0
  r.z = (int)bytes;               // num_records in bytes
  r.w = 0x00020000;               // raw dword access
  return r;
}

// grid: NN*HH*4 = 1024 blocks, 256 threads, 40 KB LDS -> 4 blocks/CU.
// block: cq = bid&3, h = (bid>>2)&63, n = bid>>8
// thread: w = t&63 (output cols 2w,2w+1), cg = t>>6; c = cq*32 + ci*4 + cg
//
// Structure: ONE global->LDS staging phase (16 lane-linear
// global_load_lds insts/wave, single latency exposure), then 8 channel
// iterations that read taps from LDS only — no global latency in the loop.
__global__ __launch_bounds__(256) void carafe_kernel(
    const float* __restrict__ feat, const float* __restrict__ masks,
    float* __restrict__ out) {
  __shared__ float sm[10240];  // 32 ch x 5 rows x 64 cols = 40 KB

  const int bid = blockIdx.x;
  const int cq = bid & 3;
  const int h  = (bid >> 2) & (HH - 1);
  const int n  = bid >> 8;
  const int t  = threadIdx.x;
  const int w  = t & (WW - 1);
  const int wv = t >> 6;  // wave id = cg

  // --- stage: 5 consecutive in-bounds rows y0..y0+4 of 32 channels ---
  // Each wave stages 8 channels; 2 insts/channel: width16 covers rows
  // y0..y0+3 (1024 B), width4 covers row y0+4 (256 B). LDS dest is
  // wave-uniform base (+lane*size by HW); global src is per-lane.
  const int y0 = min(max(h - 2, 0), HH - KK);  // clamp(h-2, 0, 59)
#pragma unroll
  for (int s = 0; s < 8; ++s) {
    const int cl = wv * 8 + s;                 // channel slot in LDS
    const float* chg =
        feat + ((size_t)(n * CC + cq * 32 + cl) * HH + y0) * WW;
    __builtin_amdgcn_global_load_lds(
        (const __attribute__((address_space(1))) void*)(chg + w * 4),
        (__attribute__((address_space(3))) void*)(sm + cl * 320), 16, 0, 0);
    __builtin_amdgcn_global_load_lds(
        (const __attribute__((address_space(1))) void*)(chg + 256 + w),
        (__attribute__((address_space(3))) void*)(sm + cl * 320 + 256), 4, 0, 0);
  }

  // --- masks -> registers with zero-padding validity folded in (R4 path);
  // overlaps the staging latency. ---
  float vi[KK], vj[KK];
#pragma unroll
  for (int i = 0; i < KK; ++i) {
    const int r = h - 2 + i;
    vi[i] = (r >= 0 && r < HH) ? 1.f : 0.f;
    const int x = w - 2 + i;
    vj[i] = (x >= 0 && x < WW) ? 1.f : 0.f;
  }
  v2f mreg[K2][2];
#pragma unroll
  for (int k = 0; k < K2; ++k) {
    const int i = k / KK, j = k % KK;
    const float vv = vi[i] * vj[j];
#pragma unroll
    for (int a = 0; a < 2; ++a) {
      const float2 mv = *reinterpret_cast<const float2*>(
          &masks[(((size_t)n * K2 + k) * HUP + (2 * h + a)) * WUP + 2 * w]);
      v2f m; m.x = mv.x * vv; m.y = mv.y * vv;
      mreg[k][a] = m;
    }
  }

  // Tap indices into the staged tile, clamped in-range; out-of-window taps
  // are annihilated by the vi/vj-zeroed mask registers.
  int ri[KK], xo[KK];
#pragma unroll
  for (int i = 0; i < KK; ++i) {
    ri[i] = min(max(h - 2 + i - y0, 0), KK - 1) * WW;  // row offset (dwords)
    xo[i] = min(max(w - 2 + i, 0), WW - 1);            // col offset (dwords)
  }

  const v4i srdO = make_srd(out, (unsigned)(NN * CC * HUP * WUP) * 4u);
  int vob = (((n * CC + cq * 32 + wv) * HUP + 2 * h) * WUP + 2 * w) * 4;

  __syncthreads();  // staging complete (compiler drains vmcnt before barrier)

#define FMA1(k, e)                                                       \
  do {                                                                   \
    v2f ff; ff.x = (e); ff.y = (e);                                      \
    acc0 += ff * mreg[k][0]; acc1 += ff * mreg[k][1];                    \
  } while (0)

  // --- compute: 8 channels per thread, LDS-only taps ---
  int cbase = wv * 320;  // dword base of this thread's channel slot
#pragma unroll 1
  for (int ci = 0; ci < 8; ++ci) {
    v2f acc0 = {0.f, 0.f}, acc1 = {0.f, 0.f};
#pragma unroll
    for (int i = 0; i < KK; ++i) {
      const int rb = cbase + ri[i];
      const float e0 = sm[rb + xo[0]];
      const float e1 = sm[rb + xo[1]];
      const float e2 = sm[rb + xo[2]];
      const float e3 = sm[rb + xo[3]];
      const float e4 = sm[rb + xo[4]];
      FMA1(i * KK + 0, e0);
      FMA1(i * KK + 1, e1);
      FMA1(i * KK + 2, e2);
      FMA1(i * KK + 3, e3);
      FMA1(i * KK + 4, e4);
    }
    llvm_amdgcn_raw_buffer_store_v2f32(acc0, srdO, vob, 0, 0);
    llvm_amdgcn_raw_buffer_store_v2f32(acc1, srdO, vob + WUP * 4, 0, 0);

    cbase += 4 * 320;            // +4 channels (cg-interleaved)
    vob += 4 * HUP * WUP * 4;
  }
#undef FMA1
}

extern "C" void kernel_launch(void* const* d_in, const int* in_sizes, int n_in,
                              void* d_out, int out_size, void* d_ws, size_t ws_size,
                              hipStream_t stream) {
  const float* feat  = (const float*)d_in[0];
  const float* masks = (const float*)d_in[1];
  float* out = (float*)d_out;
  (void)in_sizes; (void)n_in; (void)out_size; (void)d_ws; (void)ws_size;
  carafe_kernel<<<NN * HH * 4, 256, 0, stream>>>(feat, masks, out);
}

// Round 11
// 20.190 us; speedup vs baseline: 2.1805x; 1.0627x over previous
//
#include <hip/hip_runtime.h>

#define NN 4
#define CC 128
#define HH 64
#define WW 64
#define KK 5
#define K2 25
#define HUP 128
#define WUP 128

typedef int   v4i __attribute__((ext_vector_type(4)));
typedef float v2f __attribute__((ext_vector_type(2)));

__device__ void llvm_amdgcn_raw_buffer_store_v2f32(v2f data, v4i srsrc,
                                                   int voffset, int soffset,
                                                   int aux)
    __asm("llvm.amdgcn.raw.buffer.store.v2f32");

__device__ inline v4i make_srd(const void* p, unsigned bytes) {
  union { const void* p; unsigned u[2]; } a;
  a.p = p;
  v4i r;
  r.x = (int)a.u[0];
  r.y = (int)(a.u[1] & 0xffffu);  // base[47:32], stride=0
  r.z = (int)bytes;               // num_records in bytes
  r.w = 0x00020000;               // raw dword access
  return r;
}

// grid: NN*HH*4 = 1024 blocks, 256 threads, 40 KB LDS -> 4 blocks/CU.
// block: cq = bid&3, h = (bid>>2)&63, n = bid>>8
// thread: w = t&63 (output cols 2w,2w+1), cg = t>>6; c = cq*32 + ci*4 + cg
//
// R10 structure (single global->LDS staging exposure, LDS-fed loop) with the
// 5 taps/row emitted as one base + imm offsets -> 2x ds_read2_b32 + 1x
// ds_read_b32 (15 LDS insts/iter vs 25). Out-of-window taps (incl. the
// negative-base lanes w<2 and the 2-dword tail overrun) are DS out-of-range
// (return 0 / garbage) AND multiplied by the vi/vj-zeroed mask registers.
__global__ __launch_bounds__(256) void carafe_kernel(
    const float* __restrict__ feat, const float* __restrict__ masks,
    float* __restrict__ out) {
  __shared__ float sm[10240];  // 32 ch x 5 rows x 64 cols = 40 KB

  const int bid = blockIdx.x;
  const int cq = bid & 3;
  const int h  = (bid >> 2) & (HH - 1);
  const int n  = bid >> 8;
  const int t  = threadIdx.x;
  const int w  = t & (WW - 1);
  const int wv = t >> 6;  // wave id = cg

  // --- stage: 5 consecutive in-bounds rows y0..y0+4 of 32 channels ---
  const int y0 = min(max(h - 2, 0), HH - KK);  // clamp(h-2, 0, 59)
#pragma unroll
  for (int s = 0; s < 8; ++s) {
    const int cl = wv * 8 + s;                 // channel slot in LDS
    const float* chg =
        feat + ((size_t)(n * CC + cq * 32 + cl) * HH + y0) * WW;
    __builtin_amdgcn_global_load_lds(
        (const __attribute__((address_space(1))) void*)(chg + w * 4),
        (__attribute__((address_space(3))) void*)(sm + cl * 320), 16, 0, 0);
    __builtin_amdgcn_global_load_lds(
        (const __attribute__((address_space(1))) void*)(chg + 256 + w),
        (__attribute__((address_space(3))) void*)(sm + cl * 320 + 256), 4, 0, 0);
  }

  // --- masks -> registers with zero-padding validity folded in (R4 path);
  // overlaps the staging latency. ---
  float vi[KK], vj[KK];
#pragma unroll
  for (int i = 0; i < KK; ++i) {
    const int r = h - 2 + i;
    vi[i] = (r >= 0 && r < HH) ? 1.f : 0.f;
    const int x = w - 2 + i;
    vj[i] = (x >= 0 && x < WW) ? 1.f : 0.f;
  }
  v2f mreg[K2][2];
#pragma unroll
  for (int k = 0; k < K2; ++k) {
    const int i = k / KK, j = k % KK;
    const float vv = vi[i] * vj[j];
#pragma unroll
    for (int a = 0; a < 2; ++a) {
      const float2 mv = *reinterpret_cast<const float2*>(
          &masks[(((size_t)n * K2 + k) * HUP + (2 * h + a)) * WUP + 2 * w]);
      v2f m; m.x = mv.x * vv; m.y = mv.y * vv;
      mreg[k][a] = m;
    }
  }

  // Row offsets within the staged tile (clamped; invalid rows vi-masked).
  int ri[KK];
#pragma unroll
  for (int i = 0; i < KK; ++i)
    ri[i] = min(max(h - 2 + i - y0, 0), KK - 1) * WW;

  const v4i srdO = make_srd(out, (unsigned)(NN * CC * HUP * WUP) * 4u);
  int vob = (((n * CC + cq * 32 + wv) * HUP + 2 * h) * WUP + 2 * w) * 4;

  __syncthreads();  // staging complete

#define FMA1(k, e)                                                       \
  do {                                                                   \
    v2f ff; ff.x = (e); ff.y = (e);                                      \
    acc0 += ff * mreg[k][0]; acc1 += ff * mreg[k][1];                    \
  } while (0)

  const int wm2 = w - 2;

  // --- compute: 8 channels per thread, LDS-only taps ---
  int cbase = wv * 320;  // dword base of this thread's channel slot
#pragma unroll 1
  for (int ci = 0; ci < 8; ++ci) {
    v2f acc0 = {0.f, 0.f}, acc1 = {0.f, 0.f};
#pragma unroll
    for (int i = 0; i < KK; ++i) {
      const int rb = cbase + ri[i] + wm2;  // per-row base; taps at +0..+4
      const float e0 = sm[rb + 0];
      const float e1 = sm[rb + 1];
      const float e2 = sm[rb + 2];
      const float e3 = sm[rb + 3];
      const float e4 = sm[rb + 4];
      FMA1(i * KK + 0, e0);
      FMA1(i * KK + 1, e1);
      FMA1(i * KK + 2, e2);
      FMA1(i * KK + 3, e3);
      FMA1(i * KK + 4, e4);
    }
    llvm_amdgcn_raw_buffer_store_v2f32(acc0, srdO, vob, 0, 0);
    llvm_amdgcn_raw_buffer_store_v2f32(acc1, srdO, vob + WUP * 4, 0, 0);

    cbase += 4 * 320;            // +4 channels (cg-interleaved)
    vob += 4 * HUP * WUP * 4;
  }
#undef FMA1
}

extern "C" void kernel_launch(void* const* d_in, const int* in_sizes, int n_in,
                              void* d_out, int out_size, void* d_ws, size_t ws_size,
                              hipStream_t stream) {
  const float* feat  = (const float*)d_in[0];
  const float* masks = (const float*)d_in[1];
  float* out = (float*)d_out;
  (void)in_sizes; (void)n_in; (void)out_size; (void)d_ws; (void)ws_size;
  carafe_kernel<<<NN * HH * 4, 256, 0, stream>>>(feat, masks, out);
}

// Round 13
// 19.919 us; speedup vs baseline: 2.2102x; 1.0136x over previous
//
#include <hip/hip_runtime.h>

#define NN 4
#define CC 128
#define HH 64
#define WW 64
#define KK 5
#define K2 25
#define HUP 128
#define WUP 128

typedef int   v4i __attribute__((ext_vector_type(4)));
typedef float v2f __attribute__((ext_vector_type(2)));

__device__ void llvm_amdgcn_raw_buffer_store_v2f32(v2f data, v4i srsrc,
                                                   int voffset, int soffset,
                                                   int aux)
    __asm("llvm.amdgcn.raw.buffer.store.v2f32");

__device__ inline v4i make_srd(const void* p, unsigned bytes) {
  union { const void* p; unsigned u[2]; } a;
  a.p = p;
  v4i r;
  r.x = (int)a.u[0];
  r.y = (int)(a.u[1] & 0xffffu);  // base[47:32], stride=0
  r.z = (int)bytes;               // num_records in bytes
  r.w = 0x00020000;               // raw dword access
  return r;
}

// DPP wave shifts (CDNA keeps GCN3 wave_* DPP controls).
// Correct semantics (per LLVM AMDGPUAtomicOptimizer's DPP scan):
//   wave_shr:1 (0x138): data moves to HIGHER lanes -> lane w reads w-1.
//   wave_shl:1 (0x130): data moves to LOWER  lanes -> lane w reads w+1.
// bound_ctrl=true: invalid source lanes read 0. shr chain zeros lanes 0,1
// (= vj[0]/vj[1]-masked left edge); shl chain zeros lanes 62,63 (right edge).
__device__ inline float dpp_prev1(float x) {  // lane w <- w-1
  return __int_as_float(__builtin_amdgcn_update_dpp(
      0, __float_as_int(x), 0x138, 0xf, 0xf, true));
}
__device__ inline float dpp_next1(float x) {  // lane w <- w+1
  return __int_as_float(__builtin_amdgcn_update_dpp(
      0, __float_as_int(x), 0x130, 0xf, 0xf, true));
}

// grid: NN*HH*4 = 1024 blocks, 256 threads, 40 KB LDS -> 4 blocks/CU.
// block: cq = bid&3, h = (bid>>2)&63, n = bid>>8
// thread: w = t&63 (output cols 2w,2w+1), cg = t>>6; c = cq*32 + ci*4 + cg
//
// R10/R11 structure (single global->LDS staging exposure, LDS-fed loop).
// Per window row: ONE ds_read_b32 (lane w -> element w); the 4 off-center
// taps come from chained DPP wave shifts on the VALU pipe. Boundary-lane
// zeros coincide exactly with the vi/vj-zeroed mask positions.
__global__ __launch_bounds__(256) void carafe_kernel(
    const float* __restrict__ feat, const float* __restrict__ masks,
    float* __restrict__ out) {
  __shared__ float sm[10240];  // 32 ch x 5 rows x 64 cols = 40 KB

  const int bid = blockIdx.x;
  const int cq = bid & 3;
  const int h  = (bid >> 2) & (HH - 1);
  const int n  = bid >> 8;
  const int t  = threadIdx.x;
  const int w  = t & (WW - 1);
  const int wv = t >> 6;  // wave id = cg

  // --- stage: 5 consecutive in-bounds rows y0..y0+4 of 32 channels ---
  const int y0 = min(max(h - 2, 0), HH - KK);  // clamp(h-2, 0, 59)
#pragma unroll
  for (int s = 0; s < 8; ++s) {
    const int cl = wv * 8 + s;                 // channel slot in LDS
    const float* chg =
        feat + ((size_t)(n * CC + cq * 32 + cl) * HH + y0) * WW;
    __builtin_amdgcn_global_load_lds(
        (const __attribute__((address_space(1))) void*)(chg + w * 4),
        (__attribute__((address_space(3))) void*)(sm + cl * 320), 16, 0, 0);
    __builtin_amdgcn_global_load_lds(
        (const __attribute__((address_space(1))) void*)(chg + 256 + w),
        (__attribute__((address_space(3))) void*)(sm + cl * 320 + 256), 4, 0, 0);
  }

  // --- masks -> registers with zero-padding validity folded in (R4 path);
  // overlaps the staging latency. ---
  float vi[KK], vj[KK];
#pragma unroll
  for (int i = 0; i < KK; ++i) {
    const int r = h - 2 + i;
    vi[i] = (r >= 0 && r < HH) ? 1.f : 0.f;
    const int x = w - 2 + i;
    vj[i] = (x >= 0 && x < WW) ? 1.f : 0.f;
  }
  v2f mreg[K2][2];
#pragma unroll
  for (int k = 0; k < K2; ++k) {
    const int i = k / KK, j = k % KK;
    const float vv = vi[i] * vj[j];
#pragma unroll
    for (int a = 0; a < 2; ++a) {
      const float2 mv = *reinterpret_cast<const float2*>(
          &masks[(((size_t)n * K2 + k) * HUP + (2 * h + a)) * WUP + 2 * w]);
      v2f m; m.x = mv.x * vv; m.y = mv.y * vv;
      mreg[k][a] = m;
    }
  }

  // Row offsets within the staged tile (clamped; invalid rows vi-masked).
  int ri[KK];
#pragma unroll
  for (int i = 0; i < KK; ++i)
    ri[i] = min(max(h - 2 + i - y0, 0), KK - 1) * WW;

  const v4i srdO = make_srd(out, (unsigned)(NN * CC * HUP * WUP) * 4u);
  int vob = (((n * CC + cq * 32 + wv) * HUP + 2 * h) * WUP + 2 * w) * 4;

  __syncthreads();  // staging complete

#define FMA1(k, e)                                                       \
  do {                                                                   \
    v2f ff; ff.x = (e); ff.y = (e);                                      \
    acc0 += ff * mreg[k][0]; acc1 += ff * mreg[k][1];                    \
  } while (0)

  // --- compute: 8 channels per thread, 5 ds_read_b32 + 20 DPP per iter ---
  int cbase = wv * 320 + w;  // dword base of this thread's channel slot
#pragma unroll 1
  for (int ci = 0; ci < 8; ++ci) {
    v2f acc0 = {0.f, 0.f}, acc1 = {0.f, 0.f};
#pragma unroll
    for (int i = 0; i < KK; ++i) {
      const float r  = sm[cbase + ri[i]];   // lane w -> element w
      const float m1 = dpp_prev1(r);        // x = w-1
      const float m2 = dpp_prev1(m1);       // x = w-2
      const float p1 = dpp_next1(r);        // x = w+1
      const float p2 = dpp_next1(p1);       // x = w+2
      FMA1(i * KK + 0, m2);
      FMA1(i * KK + 1, m1);
      FMA1(i * KK + 2, r);
      FMA1(i * KK + 3, p1);
      FMA1(i * KK + 4, p2);
    }
    llvm_amdgcn_raw_buffer_store_v2f32(acc0, srdO, vob, 0, 0);
    llvm_amdgcn_raw_buffer_store_v2f32(acc1, srdO, vob + WUP * 4, 0, 0);

    cbase += 4 * 320;            // +4 channels (cg-interleaved)
    vob += 4 * HUP * WUP * 4;
  }
#undef FMA1
}

extern "C" void kernel_launch(void* const* d_in, const int* in_sizes, int n_in,
                              void* d_out, int out_size, void* d_ws, size_t ws_size,
                              hipStream_t stream) {
  const float* feat  = (const float*)d_in[0];
  const float* masks = (const float*)d_in[1];
  float* out = (float*)d_out;
  (void)in_sizes; (void)n_in; (void)out_size; (void)d_ws; (void)ws_size;
  carafe_kernel<<<NN * HH * 4, 256, 0, stream>>>(feat, masks, out);
}